// Round 1
// 304.219 us; speedup vs baseline: 1.0171x; 1.0171x over previous
//
#include <hip/hip_runtime.h>

typedef __attribute__((ext_vector_type(8))) __bf16 bf16x8;
typedef __attribute__((ext_vector_type(4))) __bf16 bf16x4;
typedef __attribute__((ext_vector_type(4))) float floatx4;

#define MFMA16x16x32 __builtin_amdgcn_mfma_f32_16x16x32_bf16

// async 16B/lane global->LDS; LDS dest = wave-uniform base + lane*16.
__device__ __forceinline__ void async_load16(const void* g, void* l) {
  __builtin_amdgcn_global_load_lds((const __attribute__((address_space(1))) void*)g,
                                   (__attribute__((address_space(3))) void*)l, 16, 0, 0);
}

// ---------------- merged cast fp32 -> bf16 for all 5 inputs ----------------
__global__ __launch_bounds__(256) void cast_all_kernel(const float* __restrict__ x,
                                                       const float* __restrict__ wq,
                                                       const float* __restrict__ wk,
                                                       const float* __restrict__ wv,
                                                       const float* __restrict__ wo,
                                                       __bf16* __restrict__ dst) {
  int i = blockIdx.x * blockDim.x + threadIdx.x;  // float4 units
  const float* src;
  int off;
  if (i < 2097152)      { src = x;  off = 0; }
  else if (i < 3145728) { src = wq; off = 2097152; }
  else if (i < 3407872) { src = wk; off = 3145728; }
  else if (i < 3670016) { src = wv; off = 3407872; }
  else                  { src = wo; off = 3670016; }
  float4 v = ((const float4*)src)[i - off];
  bf16x4 o;
  o[0] = (__bf16)v.x; o[1] = (__bf16)v.y; o[2] = (__bf16)v.z; o[3] = (__bf16)v.w;
  *(bf16x4*)(dst + (size_t)i * 4) = o;
}

// ---------------- GEMM: C(M,N) = A(M,K) @ B(N,K)^T, bf16 in, m97-style ----------------
// MODE 0: fp32 C store. MODE 1: fused epilogue -> qb (rope, pre-scaled by
// (1/sqrt(128))*log2(e) so attn can exp2 directly), kb (rope), vtg (transposed cast).
template <int MODE>
__global__ __launch_bounds__(256, 3) void gemm_bt(const __bf16* __restrict__ A,
                                                  const __bf16* __restrict__ Bw,
                                                  float* __restrict__ C,
                                                  const float* __restrict__ cs,
                                                  const float* __restrict__ sn,
                                                  __bf16* __restrict__ qb,
                                                  __bf16* __restrict__ kb,
                                                  __bf16* __restrict__ vtg,
                                                  int M, int N, int K) {
  __shared__ __bf16 As[128][64];
  __shared__ __bf16 Bs[128][64];
  const int tid = threadIdx.x;
  const int wave = tid >> 6, lane = tid & 63;
  const int quad = lane >> 4, l16 = lane & 15;
  const int wm = (wave >> 1) * 64, wn = (wave & 1) * 64;
  const int row0 = blockIdx.y * 128, col0 = blockIdx.x * 128;
  const int lr = lane >> 3, ls = lane & 7;
  const int segg = ls ^ lr;
  floatx4 acc[4][4] = {};
  const __bf16* Ab = A + (size_t)row0 * K + segg * 8;
  const __bf16* Bb = Bw + (size_t)col0 * K + segg * 8;
  for (int k0 = 0; k0 < K; k0 += 64) {
    __syncthreads();
#pragma unroll
    for (int i = 0; i < 4; i++) {
      int c = wave * 4 + i;
      int r = c * 8 + lr;
      async_load16(Ab + (size_t)r * K + k0, &As[c * 8][0]);
      async_load16(Bb + (size_t)r * K + k0, &Bs[c * 8][0]);
    }
    __syncthreads();
#pragma unroll
    for (int kk = 0; kk < 64; kk += 32) {
      bf16x8 af[4], bfr[4];
#pragma unroll
      for (int mt = 0; mt < 4; mt++) {
        int row = wm + mt * 16 + l16;
        int seg = ((kk >> 3) + quad) ^ (row & 7);
        af[mt] = *(const bf16x8*)&As[row][seg * 8];
      }
#pragma unroll
      for (int nt = 0; nt < 4; nt++) {
        int row = wn + nt * 16 + l16;
        int seg = ((kk >> 3) + quad) ^ (row & 7);
        bfr[nt] = *(const bf16x8*)&Bs[row][seg * 8];
      }
#pragma unroll
      for (int mt = 0; mt < 4; mt++)
#pragma unroll
        for (int nt = 0; nt < 4; nt++)
          acc[mt][nt] = MFMA16x16x32(af[mt], bfr[nt], acc[mt][nt], 0, 0, 0);
    }
  }
  if (MODE == 0) {
#pragma unroll
    for (int mt = 0; mt < 4; mt++)
#pragma unroll
      for (int nt = 0; nt < 4; nt++)
#pragma unroll
        for (int r = 0; r < 4; r++) {
          int row = row0 + wm + mt * 16 + quad * 4 + r;
          int col = col0 + wn + nt * 16 + l16;
          C[(size_t)row * N + col] = acc[mt][nt][r];
        }
  } else {
#pragma unroll
    for (int mt = 0; mt < 4; mt++)
#pragma unroll
      for (int nt = 0; nt < 4; nt++) {
        const int cbase = col0 + wn + nt * 16;  // uniform region per (wave,nt)
        const int c = cbase + l16;
#pragma unroll
        for (int r = 0; r < 4; r++) {
          int row = row0 + wm + mt * 16 + quad * 4 + r;
          int t = row & 2047;
          float v = acc[mt][nt][r];
          float vp = __shfl_xor(v, 1);  // RoPE pair partner (col ^ 1)
          if (cbase < 2048) {           // Q + RoPE, pre-scaled for exp2 softmax
            int i = (c & 127) >> 1;
            float co = cs[t * 64 + i], si = sn[t * 64 + i];
            qb[(size_t)row * 2048 + c] =
                (__bf16)((v * co + ((c & 1) ? vp : -vp) * si) * 0.1275411391f);
          } else if (cbase < 2560) {    // K + RoPE
            int i = (c & 127) >> 1;
            float co = cs[t * 64 + i], si = sn[t * 64 + i];
            kb[(size_t)row * 512 + c - 2048] = (__bf16)(v * co + ((c & 1) ? vp : -vp) * si);
          } else {                      // V: store transposed [d][t]
            int vd = c - 2560;
            vtg[((size_t)(row >> 11) * 512 + vd) * 2048 + t] = (__bf16)v;
          }
        }
      }
  }
}

// ---------------- Flash attention, causal, GQA; double-buffered K/V ----------------
// Identical schedule/layout to previous version; all swizzled LDS addresses are
// algebraically decomposed into hoisted per-lane byte bases + compile-time
// ds-offset immediates (XOR swizzle bits split: bits0-1 lane-only, bit2 = two
// base variants, bit3 = immediate). Kills ~450 VALU-cycles/iter of address
// recomputation. Q arrives pre-scaled by cexp, so softmax is a bare exp2.
__global__ __launch_bounds__(256, 2) void attn_kernel(const __bf16* __restrict__ qb,
                                                      const __bf16* __restrict__ kb,
                                                      const __bf16* __restrict__ vtg,
                                                      __bf16* __restrict__ yb) {
  const int id = blockIdx.x;
  const int q1 = id >> 8;              // 0..1
  const int cc = id & 255;
  const int kvh = cc & 3;
  const int b = (cc >> 2) & 1;
  const int s5 = (cc >> 3) & 31;
  const int tile = q1 ? (63 - s5) : s5;  // bijective over 0..63
  const int tid = threadIdx.x, wave = tid >> 6, lane = tid & 63;
  const int h = kvh * 4 + wave;
  const int quad = lane >> 4, l16 = lane & 15;
  const int q0 = tile * 32;
  __shared__ __bf16 Ks[2][64][128];      // [buf][key][dim], swizzled (32 KB)
  __shared__ __bf16 Vt[2][128][64];      // [buf][dim][key], swizzled (32 KB)
  __shared__ __bf16 Ps[4][2][16][64];    // per-wave, per-m-tile P strip (16 KB)
  const __bf16* kbase = kb + (size_t)b * 2048 * 512 + kvh * 128;
  const __bf16* vbase = vtg + ((size_t)b * 512 + kvh * 128) * 2048;

  // ---- hoisted lane-dependent LDS byte bases (loop-invariant) ----
  // XOR-seg decomposition: seg=(c*4+quad)^(l16&7) -> 16*(quad^(l16&3)) [lane]
  //   + 64*((c&1)^b2) [2 base variants] + 128*(c>>1) [immediate].
  const int u16   = (quad ^ (l16 & 3)) * 16;
  const int b2_64 = (l16 & 4) ? 64 : 0;
  char* const ksb = (char*)Ks;
  char* const vtb = (char*)Vt;
  char* const psb = (char*)Ps + wave * 4096;
  char* const kA0 = ksb + l16 * 256 + u16 + b2_64;   // K frag, kc even, buf0
  char* const kB0 = kA0 + 64 - 2 * b2_64;            // K frag, kc odd,  buf0
  char* const kA1 = kA0 + 16384;
  char* const kB1 = kB0 + 16384;
  char* const vA0 = vtb + l16 * 128 + u16 + b2_64;   // V frag, c2=0, buf0
  char* const vB0 = vA0 + 64 - 2 * b2_64;            // V frag, c2=1, buf0
  char* const vA1 = vA0 + 16384;
  char* const vB1 = vB0 + 16384;
  char* const prA = psb + l16 * 128 + u16 + b2_64;   // Ps read, c2=0 (+mt*2048)
  char* const prB = prA + 64 - 2 * b2_64;            // Ps read, c2=1
  // Ps write: byte = quad*512 + (l16&7)*2 + 16*(h^(r&1)) + 32*((nt&1)^(r>>1))
  //           + 64*((nt>>1)^(quad&1)) + r*128 + mt*2048
  const int h16 = (l16 & 8) ? 16 : 0;
  const int q64 = (quad & 1) * 64;
  char* const pw00 = psb + quad * 512 + (l16 & 7) * 2 + h16 + q64;         // r even, nt<2
  char* const pw10 = psb + quad * 512 + (l16 & 7) * 2 + (16 - h16) + q64;  // r odd,  nt<2
  char* const pw01 = pw00 + 64 - 2 * q64;                                  // r even, nt>=2
  char* const pw11 = pw10 + 64 - 2 * q64;                                  // r odd,  nt>=2

  // ---- hoisted staging source pointers (global) ----
  const int klr4 = lane >> 4, kls = lane & 15;
  const int vlr8 = lane >> 3, vls = lane & 7;
  const __bf16* ksrc[4];
  const __bf16* vsrc[4];
#pragma unroll
  for (int i = 0; i < 4; i++) {
    int row = (wave * 4 + i) * 4 + klr4;
    ksrc[i] = kbase + (size_t)row * 512 + (kls ^ (row & 7)) * 8;
    int d = (wave * 4 + i) * 8 + vlr8;
    vsrc[i] = vbase + (size_t)d * 2048 + (vls ^ (d & 7)) * 8;
  }
  char* const kdst = ksb + wave * 4096;
  char* const vdst = vtb + wave * 4096;

  auto stage = [&](int pb, int s0) {
#pragma unroll
    for (int i = 0; i < 4; i++)   // K: 64 keys x 128 dims
      async_load16(ksrc[i] + (size_t)s0 * 512, kdst + pb * 16384 + i * 1024);
#pragma unroll
    for (int i = 0; i < 4; i++)   // Vt: 128 dims x 64 keys
      async_load16(vsrc[i] + s0, vdst + pb * 16384 + i * 1024);
  };

  bf16x8 qf[2][4];
#pragma unroll
  for (int mt = 0; mt < 2; mt++)
#pragma unroll
    for (int kc = 0; kc < 4; kc++)
      qf[mt][kc] = *(const bf16x8*)(qb + (size_t)(b * 2048 + q0 + mt * 16 + l16) * 2048 +
                                    h * 128 + kc * 32 + quad * 8);
  bf16x8 ones;
#pragma unroll
  for (int j = 0; j < 8; j++) ones[j] = (__bf16)1.0f;
  floatx4 o[2][8] = {};
  floatx4 lsum[2] = {};
  const int nblocks = (tile + 2) >> 1;  // ceil((q0+32)/64)

  stage(0, 0);
  __syncthreads();  // buf0 staged (compiler drains vmcnt before barrier)

  for (int it = 0; it < nblocks; it++) {
    const int cur = it & 1;
    const int s0 = it * 64;
    if (it + 1 < nblocks) stage(cur ^ 1, s0 + 64);  // prefetch next, other buffer
    const char* kA = cur ? kA1 : kA0;
    const char* kB = cur ? kB1 : kB0;
    const char* vA = cur ? vA1 : vA0;
    const char* vB = cur ? vB1 : vB0;
    // QK^T: 32 q rows x 64 keys (K-frags shared by both m-tiles)
    floatx4 sacc[2][4] = {};
    __builtin_amdgcn_s_setprio(1);
#pragma unroll
    for (int kc = 0; kc < 4; kc++) {
      const char* kbp = (kc & 1) ? kB : kA;
      bf16x8 bfr[4];
#pragma unroll
      for (int nt = 0; nt < 4; nt++)
        bfr[nt] = *(const bf16x8*)(kbp + nt * 4096 + (kc >> 1) * 128);
#pragma unroll
      for (int mt = 0; mt < 2; mt++)
#pragma unroll
        for (int nt = 0; nt < 4; nt++)
          sacc[mt][nt] = MFMA16x16x32(qf[mt][kc], bfr[nt], sacc[mt][nt], 0, 0, 0);
    }
    __builtin_amdgcn_s_setprio(0);
    // P = exp2(S) (scale pre-folded into Q), masked on diagonal block
    const bool diag = (it == nblocks - 1);
#pragma unroll
    for (int mt = 0; mt < 2; mt++)
#pragma unroll
      for (int r = 0; r < 4; r++) {
        const int qg = q0 + mt * 16 + quad * 4 + r;
#pragma unroll
        for (int nt = 0; nt < 4; nt++) {
          float p = __builtin_exp2f(sacc[mt][nt][r]);
          if (diag) { int keyg = s0 + nt * 16 + l16; p = (keyg <= qg) ? p : 0.f; }
          char* w = (r & 1) ? ((nt < 2) ? pw10 : pw11) : ((nt < 2) ? pw00 : pw01);
          *(__bf16*)(w + mt * 2048 + r * 128 + ((nt & 1) ^ (r >> 1)) * 32) = (__bf16)p;
        }
      }
    // P @ V (+ ones for row sums). Same-wave Ps write->read: no barrier.
    __builtin_amdgcn_s_setprio(1);
#pragma unroll
    for (int c2 = 0; c2 < 2; c2++) {
      const char* pr = c2 ? prB : prA;
      const char* vv = c2 ? vB : vA;
      bf16x8 pa[2];
#pragma unroll
      for (int mt = 0; mt < 2; mt++) {
        pa[mt] = *(const bf16x8*)(pr + mt * 2048);
        lsum[mt] = MFMA16x16x32(pa[mt], ones, lsum[mt], 0, 0, 0);
      }
#pragma unroll
      for (int dt = 0; dt < 8; dt++) {
        bf16x8 vf = *(const bf16x8*)(vv + dt * 2048);
#pragma unroll
        for (int mt = 0; mt < 2; mt++)
          o[mt][dt] = MFMA16x16x32(pa[mt], vf, o[mt][dt], 0, 0, 0);
      }
    }
    __builtin_amdgcn_s_setprio(0);
    __syncthreads();  // drains prefetch DMA; frees buf `cur` for iter it+1's prefetch
  }
#pragma unroll
  for (int mt = 0; mt < 2; mt++) {
    float inv[4];
#pragma unroll
    for (int r = 0; r < 4; r++) inv[r] = 1.f / lsum[mt][r];
#pragma unroll
    for (int dt = 0; dt < 8; dt++)
#pragma unroll
      for (int r = 0; r < 4; r++) {
        int qg = q0 + mt * 16 + quad * 4 + r;
        yb[(size_t)(b * 2048 + qg) * 2048 + h * 128 + dt * 16 + l16] =
            (__bf16)(o[mt][dt][r] * inv[r]);
      }
  }
}

// ---------------- host ----------------
extern "C" void kernel_launch(void* const* d_in, const int* in_sizes, int n_in,
                              void* d_out, int out_size, void* d_ws, size_t ws_size,
                              hipStream_t stream) {
  const float* x  = (const float*)d_in[0];
  const float* fc = (const float*)d_in[1];
  const float* fs = (const float*)d_in[2];
  const float* wq = (const float*)d_in[3];
  const float* wk = (const float*)d_in[4];
  const float* wv = (const float*)d_in[5];
  const float* wo = (const float*)d_in[6];
  float* out = (float*)d_out;
  char* ws = (char*)d_ws;

  __bf16* xb   = (__bf16*)(ws);              // 4096x2048 bf16
  __bf16* wqkv = (__bf16*)(ws + 16777216);   // 3072x2048 bf16 (wq|wk|wv)
  __bf16* wob  = (__bf16*)(ws + 29360128);   // 2048x2048 bf16
  __bf16* qbuf = (__bf16*)(ws + 37748736);   // 4096x2048 bf16 (roped, pre-scaled)
  __bf16* kbuf = (__bf16*)(ws + 54525952);   // 4096x512 bf16 (roped)
  __bf16* vtg  = (__bf16*)(ws + 58720256);   // 1024x2048 bf16 (V^T per b,kvh)
  __bf16* ybuf = (__bf16*)(ws + 62914560);   // 4096x2048 bf16

  // one merged cast launch (dst regions contiguous from ws+0)
  cast_all_kernel<<<18432, 256, 0, stream>>>(x, wq, wk, wv, wo, xb);

  // QKV projection with fused RoPE + transposed-V epilogue (M=4096, N=3072, K=2048)
  gemm_bt<1><<<dim3(24, 32), 256, 0, stream>>>(xb, wqkv, nullptr, fc, fs,
                                               qbuf, kbuf, vtg, 4096, 3072, 2048);

  // flash attention: 512 4-wave WGs, 32 q-rows/wave, double-buffered K/V
  attn_kernel<<<dim3(512), 256, 0, stream>>>(qbuf, kbuf, vtg, ybuf);

  // output projection: out = y @ wo^T (M=4096, N=2048, K=2048)
  gemm_bt<0><<<dim3(16, 32), 256, 0, stream>>>(ybuf, wob, out, nullptr, nullptr,
                                               nullptr, nullptr, nullptr, 4096, 2048, 2048);
}